// Round 1
// baseline (5656.127 us; speedup 1.0000x reference)
//
#include <hip/hip_runtime.h>
#include <math.h>

// ---------------------------------------------------------------------------
// DiscriminatorLSTM: B=128, T=64, FEAT=4096, FUSION=1024, H=1024, C=2
//
// Decomposition:
//   Phase A (parallel): F[8192,1024]  = relu(X[8192,4096] @ W_feat^T + b_feat)
//   Phase B (parallel): Gx[8192,4096] = F @ W_ih^T + b_ih
//   Phase C (seq, t=0..63): gates = Gx[rows b*64+t] + h @ W_hh^T + b_hh
//                           LSTM cell -> h,c ; store h into H_all row b*64+t
//   Phase D (parallel): out[8192,2] = H_all @ W_cls^T + b_cls
//
// Workspace layout (requires ws_size >= ~161 MB):
//   [0, 32MB)      F  (8192*1024 f32)  -- reused as H_all during phase C
//   [32MB, 160MB)  Gx (8192*4096 f32)  -- gates written in-place per step
//   [160MB, ...)   h (128*1024), c (128*1024)
// ---------------------------------------------------------------------------

__global__ void zero_f32(float* __restrict__ p, int n) {
    int i = blockIdx.x * blockDim.x + threadIdx.x;
    if (i < n) p[i] = 0.f;
}

// C[m,n] = sum_k A[m,k]*B[n,k] + bias[n] (+C_in) (optional relu)
// A row-major [M,K] lda, B row-major [N,K] ldb (i.e. C = A @ B^T)
template<int BM, int BN, int BK, int TM, int TN, bool RELU, bool ADDC>
__global__ __launch_bounds__((BM / TM) * (BN / TN))
void gemm_nt(const float* __restrict__ A, int lda,
             const float* __restrict__ B, int ldb,
             const float* __restrict__ bias,
             float* __restrict__ C, long ldc,
             int M, int N, int K)
{
    constexpr int NT = (BM / TM) * (BN / TN);
    __shared__ float As[BK][BM + 4];   // +4 pad keeps 16B alignment, breaks pow2 stride
    __shared__ float Bs[BK][BN + 4];

    const int tid  = threadIdx.x;
    const int bm   = blockIdx.x * BM;
    const int bn   = blockIdx.y * BN;
    const int tcol = tid % (BN / TN);
    const int trow = tid / (BN / TN);

    float acc[TM][TN];
#pragma unroll
    for (int i = 0; i < TM; ++i)
#pragma unroll
        for (int j = 0; j < TN; ++j) acc[i][j] = 0.f;

    for (int k0 = 0; k0 < K; k0 += BK) {
        constexpr int AV = BM * BK / 4;   // float4 loads for A tile
#pragma unroll
        for (int i = tid; i < AV; i += NT) {
            int m  = i / (BK / 4);
            int kq = (i % (BK / 4)) * 4;
            const float4 v = *(const float4*)(A + (size_t)(bm + m) * lda + k0 + kq);
            As[kq + 0][m] = v.x; As[kq + 1][m] = v.y;
            As[kq + 2][m] = v.z; As[kq + 3][m] = v.w;
        }
        constexpr int BV = BN * BK / 4;
#pragma unroll
        for (int i = tid; i < BV; i += NT) {
            int n  = i / (BK / 4);
            int kq = (i % (BK / 4)) * 4;
            const float4 v = *(const float4*)(B + (size_t)(bn + n) * ldb + k0 + kq);
            Bs[kq + 0][n] = v.x; Bs[kq + 1][n] = v.y;
            Bs[kq + 2][n] = v.z; Bs[kq + 3][n] = v.w;
        }
        __syncthreads();
#pragma unroll
        for (int k = 0; k < BK; ++k) {
            float a[TM], b[TN];
#pragma unroll
            for (int i = 0; i < TM; ++i) a[i] = As[k][trow * TM + i];
#pragma unroll
            for (int j = 0; j < TN; ++j) b[j] = Bs[k][tcol * TN + j];
#pragma unroll
            for (int i = 0; i < TM; ++i)
#pragma unroll
                for (int j = 0; j < TN; ++j)
                    acc[i][j] = fmaf(a[i], b[j], acc[i][j]);
        }
        __syncthreads();
    }

#pragma unroll
    for (int i = 0; i < TM; ++i) {
        const int m = bm + trow * TM + i;
#pragma unroll
        for (int j = 0; j < TN; ++j) {
            const int n = bn + tcol * TN + j;
            float v = acc[i][j] + bias[n];
            if (ADDC) v += C[(size_t)m * ldc + n];
            if (RELU) v = fmaxf(v, 0.f);
            C[(size_t)m * ldc + n] = v;
        }
    }
}

__device__ __forceinline__ float sigmoidf_(float x) {
    return 1.f / (1.f + __expf(-x));
}

// gates: [128 rows at stride ldg][4096], torch LSTMCell order i,f,g,o
__global__ void lstm_cell(const float* __restrict__ gates, long ldg,
                          float* __restrict__ c, float* __restrict__ h,
                          float* __restrict__ Hall, int t)
{
    int idx = blockIdx.x * blockDim.x + threadIdx.x;   // 0 .. 128*1024-1
    int b = idx >> 10;
    int j = idx & 1023;
    const float* grow = gates + (size_t)b * ldg;
    float ig = sigmoidf_(grow[j]);
    float fg = sigmoidf_(grow[1024 + j]);
    float g  = tanhf(grow[2048 + j]);
    float og = sigmoidf_(grow[3072 + j]);
    float cn = fg * c[idx] + ig * g;
    float hn = og * tanhf(cn);
    c[idx] = cn;
    h[idx] = hn;
    Hall[((size_t)b * 64 + t) * 1024 + j] = hn;
}

// out[r,c] = sum_j Hall[r,j] * Wc[c,j] + bc[c]   (one wave per row)
__global__ void cls_scores(const float* __restrict__ Hall,
                           const float* __restrict__ Wc,
                           const float* __restrict__ bc,
                           float* __restrict__ out)
{
    int wave = (blockIdx.x * blockDim.x + threadIdx.x) >> 6;
    int lane = threadIdx.x & 63;
    if (wave >= 8192) return;
    const float* hrow = Hall + (size_t)wave * 1024;
    float s0 = 0.f, s1 = 0.f;
    for (int j = lane; j < 1024; j += 64) {
        float hv = hrow[j];
        s0 += hv * Wc[j];
        s1 += hv * Wc[1024 + j];
    }
#pragma unroll
    for (int off = 32; off > 0; off >>= 1) {
        s0 += __shfl_down(s0, off);
        s1 += __shfl_down(s1, off);
    }
    if (lane == 0) {
        out[(size_t)wave * 2 + 0] = s0 + bc[0];
        out[(size_t)wave * 2 + 1] = s1 + bc[1];
    }
}

extern "C" void kernel_launch(void* const* d_in, const int* in_sizes, int n_in,
                              void* d_out, int out_size, void* d_ws, size_t ws_size,
                              hipStream_t stream) {
    const float* x      = (const float*)d_in[0];
    const float* W_feat = (const float*)d_in[1];
    const float* b_feat = (const float*)d_in[2];
    const float* W_ih   = (const float*)d_in[3];
    const float* b_ih   = (const float*)d_in[4];
    const float* W_hh   = (const float*)d_in[5];
    const float* b_hh   = (const float*)d_in[6];
    const float* W_cls  = (const float*)d_in[7];
    const float* b_cls  = (const float*)d_in[8];
    float* out = (float*)d_out;

    char* ws = (char*)d_ws;
    float* F  = (float*)ws;                       // 8192*1024 (32 MB); later H_all
    float* Gx = (float*)(ws + 33554432);          // 8192*4096 (128 MB)
    float* h  = (float*)(ws + 167772160);         // 128*1024
    float* c  = h + 131072;                       // 128*1024

    // init h = c = 0 (ws is poisoned, not re-poisoned between replays)
    zero_f32<<<dim3(1024), dim3(256), 0, stream>>>(h, 262144);

    // Phase A: F = relu(X @ W_feat^T + b_feat)   M=8192 N=1024 K=4096
    gemm_nt<128, 128, 16, 8, 8, true, false>
        <<<dim3(8192 / 128, 1024 / 128), 256, 0, stream>>>(
            x, 4096, W_feat, 4096, b_feat, F, 1024, 8192, 1024, 4096);

    // Phase B: Gx = F @ W_ih^T + b_ih            M=8192 N=4096 K=1024
    gemm_nt<128, 128, 16, 8, 8, false, false>
        <<<dim3(8192 / 128, 4096 / 128), 256, 0, stream>>>(
            F, 1024, W_ih, 1024, b_ih, Gx, 4096, 8192, 4096, 1024);

    // Phase C: sequential recurrence over T=64
    for (int t = 0; t < 64; ++t) {
        // gates(rows b*64+t of Gx) += h @ W_hh^T + b_hh   M=128 N=4096 K=1024
        gemm_nt<32, 64, 32, 2, 4, false, true>
            <<<dim3(128 / 32, 4096 / 64), 256, 0, stream>>>(
                h, 1024, W_hh, 1024, b_hh, Gx + (size_t)t * 4096, 64 * 4096,
                128, 4096, 1024);
        lstm_cell<<<dim3(512), dim3(256), 0, stream>>>(
            Gx + (size_t)t * 4096, 64 * 4096, c, h, F /*H_all*/, t);
    }

    // Phase D: out = H_all @ W_cls^T + b_cls
    cls_scores<<<dim3(2048), dim3(256), 0, stream>>>(F, W_cls, b_cls, out);
}

// Round 2
// 2553.034 us; speedup vs baseline: 2.2155x; 2.2155x over previous
//
#include <hip/hip_runtime.h>
#include <math.h>

// ---------------------------------------------------------------------------
// DiscriminatorLSTM: B=128, T=64, FEAT=4096, FUSION=1024, H=1024, C=2
//
// Phase A (fp32 tile GEMM): F[8192,1024]  = relu(X @ W_feat^T + b_feat)
// Phase B (fp32 tile GEMM): Gx[8192,4096] = F @ W_ih^T + b_ih
// pack_whh: W_hh -> split-bf16 (hi/lo) MFMA B-fragment layout (16 MB)
// Phase C: 64x lstm_step (one kernel per timestep):
//    gates = Gx[t] + b_hh + h @ W_hh^T   (split-bf16 MFMA, 3 products)
//    LSTM cell -> h (stored as A-fragments, double-buffered), c
//    scores partial = h_slice @ W_cls^T  -> atomicAdd into d_out
//
// Workspace layout (<= 160 MB, proven available in round 1):
//   [0, 32MB)    F (phase A out / phase B in). After phase B this region is
//                overlaid with: Wf (16 MB @ 0), hfrag (1 MB @ 16MB), c (@17MB)
//   [32MB,160MB) Gx
// ---------------------------------------------------------------------------

typedef __attribute__((ext_vector_type(8))) short short8v;   // 8 bf16
typedef __attribute__((ext_vector_type(4))) float f32x4;

#define WF_LO_OFF 8388608u    // lo fragments at +8 MB inside Wf
#define HF_BUF    524288      // h-frag double-buffer stride
#define HF_HL     262144      // hi/lo stride
#define HF_MT     32768       // m_tile stride

__device__ __forceinline__ unsigned short f2bf(float f) {   // RNE f32->bf16
    unsigned u = __builtin_bit_cast(unsigned, f);
    u = (u + 0x7fffu + ((u >> 16) & 1u)) >> 16;
    return (unsigned short)u;
}
__device__ __forceinline__ float bf2f(unsigned short b) {
    unsigned u = ((unsigned)b) << 16;
    return __builtin_bit_cast(float, u);
}

// ----------------------- fp32 tile GEMM (phases A/B) -----------------------
template<int BM, int BN, int BK, int TM, int TN, bool RELU>
__global__ __launch_bounds__((BM / TM) * (BN / TN))
void gemm_nt(const float* __restrict__ A, int lda,
             const float* __restrict__ B, int ldb,
             const float* __restrict__ bias,
             float* __restrict__ C, long ldc,
             int M, int N, int K)
{
    constexpr int NT = (BM / TM) * (BN / TN);
    __shared__ float As[BK][BM + 4];
    __shared__ float Bs[BK][BN + 4];

    const int tid  = threadIdx.x;
    const int bm   = blockIdx.x * BM;
    const int bn   = blockIdx.y * BN;
    const int tcol = tid % (BN / TN);
    const int trow = tid / (BN / TN);

    float acc[TM][TN];
#pragma unroll
    for (int i = 0; i < TM; ++i)
#pragma unroll
        for (int j = 0; j < TN; ++j) acc[i][j] = 0.f;

    for (int k0 = 0; k0 < K; k0 += BK) {
        constexpr int AV = BM * BK / 4;
#pragma unroll
        for (int i = tid; i < AV; i += NT) {
            int m  = i / (BK / 4);
            int kq = (i % (BK / 4)) * 4;
            const float4 v = *(const float4*)(A + (size_t)(bm + m) * lda + k0 + kq);
            As[kq + 0][m] = v.x; As[kq + 1][m] = v.y;
            As[kq + 2][m] = v.z; As[kq + 3][m] = v.w;
        }
        constexpr int BV = BN * BK / 4;
#pragma unroll
        for (int i = tid; i < BV; i += NT) {
            int n  = i / (BK / 4);
            int kq = (i % (BK / 4)) * 4;
            const float4 v = *(const float4*)(B + (size_t)(bn + n) * ldb + k0 + kq);
            Bs[kq + 0][n] = v.x; Bs[kq + 1][n] = v.y;
            Bs[kq + 2][n] = v.z; Bs[kq + 3][n] = v.w;
        }
        __syncthreads();
#pragma unroll
        for (int k = 0; k < BK; ++k) {
            float a[TM], b[TN];
#pragma unroll
            for (int i = 0; i < TM; ++i) a[i] = As[k][trow * TM + i];
#pragma unroll
            for (int j = 0; j < TN; ++j) b[j] = Bs[k][tcol * TN + j];
#pragma unroll
            for (int i = 0; i < TM; ++i)
#pragma unroll
                for (int j = 0; j < TN; ++j)
                    acc[i][j] = fmaf(a[i], b[j], acc[i][j]);
        }
        __syncthreads();
    }

#pragma unroll
    for (int i = 0; i < TM; ++i) {
        const int m = bm + trow * TM + i;
#pragma unroll
        for (int j = 0; j < TN; ++j) {
            const int n = bn + tcol * TN + j;
            float v = acc[i][j] + bias[n];
            if (RELU) v = fmaxf(v, 0.f);
            C[(size_t)m * ldc + n] = v;
        }
    }
}

// --------------- W_hh -> split-bf16 B-fragment pre-pack --------------------
// Fragment (ng,g,kc,nt): 64 lanes x 8 bf16 (1 KB). Element mapping for the
// mfma_16x16x32 B operand: n = lane&15, k = (lane>>4)*8 + e.
__global__ void pack_whh(const float* __restrict__ W, char* __restrict__ Wf) {
    int gid = blockIdx.x * blockDim.x + threadIdx.x;   // < 524288
    int l = gid & 63, fid = gid >> 6;
    int nt = fid & 1, kc = (fid >> 1) & 31, g = (fid >> 6) & 3, ng = fid >> 8;
    int n = g * 1024 + ng * 32 + nt * 16 + (l & 15);
    int k = kc * 32 + (l >> 4) * 8;
    const float* src = W + (size_t)n * 1024 + k;
    short8v hi, lo;
#pragma unroll
    for (int e = 0; e < 8; ++e) {
        float v = src[e];
        unsigned short hb = f2bf(v);
        hi[e] = (short)hb;
        lo[e] = (short)f2bf(v - bf2f(hb));
    }
    size_t off = (size_t)fid * 1024 + (size_t)l * 16;
    *(short8v*)(Wf + off) = hi;
    *(short8v*)(Wf + WF_LO_OFF + off) = lo;
}

__global__ void out_init(float* __restrict__ out, const float* __restrict__ b_cls) {
    int i = blockIdx.x * blockDim.x + threadIdx.x;
    if (i < 16384) out[i] = b_cls[i & 1];
}

// --------------------------- fused LSTM step -------------------------------
// Grid 256 (1 WG/CU), 256 threads (4 waves = 4 gates). WG (m_tile, ng)
// computes gate tile [16 rows x 4x32 cols], cell for h[16 x 32], h-frag
// write-out, and the classifier partial for its 32 h-columns.
__global__ __launch_bounds__(256)
void lstm_step(const float* __restrict__ Gx,
               const float* __restrict__ b_hh,
               const char*  __restrict__ Wf,
               char*        __restrict__ hfrag,
               float*       __restrict__ c,
               const float* __restrict__ Wc,
               float*       __restrict__ out,
               int t)
{
    __shared__ float gates_s[4][16][33];
    __shared__ float h_s[16][33];
    __shared__ float Wc_s[2][32];

    const int tid  = threadIdx.x;
    const int bid  = blockIdx.x;
    const int g    = tid >> 6;         // wave = gate (torch order i,f,g,o)
    const int l    = tid & 63;
    const int slot = bid >> 3;
    const int m_tile = slot & 7;               // 8 row-tiles of 16
    const int ng   = (bid & 7) * 4 + (slot >> 3);  // XCD-grouped col-chunk

    if (tid < 64) Wc_s[tid >> 5][tid & 31] =
        Wc[(size_t)(tid >> 5) * 1024 + ng * 32 + (tid & 31)];

    const int lhi = l >> 4;   // 0..3
    const int llo = l & 15;

    const float bh0 = b_hh[g * 1024 + ng * 32 + llo];
    const float bh1 = b_hh[g * 1024 + ng * 32 + 16 + llo];

    // acc init from Gx + b_hh  (D layout: n = lane&15, m = (lane>>4)*4+reg)
    f32x4 acc0, acc1;
    {
        const int colg0 = g * 1024 + ng * 32 + llo;
#pragma unroll
        for (int r = 0; r < 4; ++r) {
            int brow = m_tile * 16 + lhi * 4 + r;
            const float* gp = Gx + ((size_t)brow * 64 + t) * 4096 + colg0;
            acc0[r] = gp[0]  + bh0;
            acc1[r] = gp[16] + bh1;
        }
    }

    if (t > 0) {
        // h A-fragments (previous step's buffer) + W B-fragments, split-bf16:
        // acc += Ah*Bh + Ah*Bl + Al*Bh
        const char* ha = hfrag + ((t - 1) & 1) * HF_BUF + m_tile * HF_MT + l * 16;
        const char* hb = ha + HF_HL;
        const char* wbase = Wf + (size_t)((ng * 4 + g) * 64) * 1024 + l * 16;
#pragma unroll 4
        for (int kc = 0; kc < 32; ++kc) {
            short8v ah = *(const short8v*)(ha + kc * 1024);
            short8v al = *(const short8v*)(hb + kc * 1024);
            const char* w0 = wbase + kc * 2048;
            short8v bhv0 = *(const short8v*)(w0);
            short8v bhv1 = *(const short8v*)(w0 + 1024);
            short8v blv0 = *(const short8v*)(w0 + WF_LO_OFF);
            short8v blv1 = *(const short8v*)(w0 + WF_LO_OFF + 1024);
            acc0 = __builtin_amdgcn_mfma_f32_16x16x32_bf16(ah, bhv0, acc0, 0, 0, 0);
            acc1 = __builtin_amdgcn_mfma_f32_16x16x32_bf16(ah, bhv1, acc1, 0, 0, 0);
            acc0 = __builtin_amdgcn_mfma_f32_16x16x32_bf16(al, bhv0, acc0, 0, 0, 0);
            acc1 = __builtin_amdgcn_mfma_f32_16x16x32_bf16(al, bhv1, acc1, 0, 0, 0);
            acc0 = __builtin_amdgcn_mfma_f32_16x16x32_bf16(ah, blv0, acc0, 0, 0, 0);
            acc1 = __builtin_amdgcn_mfma_f32_16x16x32_bf16(ah, blv1, acc1, 0, 0, 0);
        }
    }

    // gates -> LDS
#pragma unroll
    for (int r = 0; r < 4; ++r) {
        gates_s[g][lhi * 4 + r][llo]      = acc0[r];
        gates_s[g][lhi * 4 + r][16 + llo] = acc1[r];
    }
    __syncthreads();

    // LSTM cell: 512 elems, 2 per thread
    for (int e = tid; e < 512; e += 256) {
        int m  = e >> 5;
        int cc = e & 31;
        float ig = gates_s[0][m][cc], fg = gates_s[1][m][cc];
        float gg = gates_s[2][m][cc], og = gates_s[3][m][cc];
        ig = 1.f / (1.f + __expf(-ig));
        fg = 1.f / (1.f + __expf(-fg));
        gg = tanhf(gg);
        og = 1.f / (1.f + __expf(-og));
        size_t cidx = (size_t)(m_tile * 16 + m) * 1024 + ng * 32 + cc;
        float cp = (t > 0) ? c[cidx] : 0.f;
        float cn = fg * cp + ig * gg;
        float hn = og * tanhf(cn);
        c[cidx] = cn;
        h_s[m][cc] = hn;
    }
    __syncthreads();

    if (g < 2) {
        // write h as A-fragment (m = lane&15, k = (lane>>4)*8+e); g=0 hi, g=1 lo
        short8v v;
#pragma unroll
        for (int e = 0; e < 8; ++e) {
            float hv = h_s[llo][lhi * 8 + e];
            unsigned short hb_ = f2bf(hv);
            v[e] = (short)(g == 0 ? hb_ : f2bf(hv - bf2f(hb_)));
        }
        char* dst = hfrag + (t & 1) * HF_BUF + g * HF_HL + m_tile * HF_MT
                  + ng * 1024 + l * 16;
        *(short8v*)dst = v;
    } else if (g == 2 && l < 32) {
        // classifier partial over this WG's 32 h-columns
        int m = l & 15, cls = l >> 4;
        float s = 0.f;
#pragma unroll
        for (int cc = 0; cc < 32; ++cc) s += h_s[m][cc] * Wc_s[cls][cc];
        atomicAdd(out + ((size_t)(m_tile * 16 + m) * 64 + t) * 2 + cls, s);
    }
}

// ---------------------------------------------------------------------------
extern "C" void kernel_launch(void* const* d_in, const int* in_sizes, int n_in,
                              void* d_out, int out_size, void* d_ws, size_t ws_size,
                              hipStream_t stream) {
    const float* x      = (const float*)d_in[0];
    const float* W_feat = (const float*)d_in[1];
    const float* b_feat = (const float*)d_in[2];
    const float* W_ih   = (const float*)d_in[3];
    const float* b_ih   = (const float*)d_in[4];
    const float* W_hh   = (const float*)d_in[5];
    const float* b_hh   = (const float*)d_in[6];
    const float* W_cls  = (const float*)d_in[7];
    const float* b_cls  = (const float*)d_in[8];
    float* out = (float*)d_out;

    char* ws = (char*)d_ws;
    float* F     = (float*)ws;                     // 32 MB (phases A/B only)
    float* Gx    = (float*)(ws + 33554432);        // 128 MB
    char*  Wf    = ws;                             // 16 MB (after B)
    char*  hfrag = ws + 16777216;                  // 1 MB
    float* c     = (float*)(ws + 17825792);        // 512 KB

    // Phase A: F = relu(X @ W_feat^T + b_feat)   M=8192 N=1024 K=4096
    gemm_nt<128, 128, 16, 8, 8, true>
        <<<dim3(8192 / 128, 1024 / 128), 256, 0, stream>>>(
            x, 4096, W_feat, 4096, b_feat, F, 1024, 8192, 1024, 4096);

    // Phase B: Gx = F @ W_ih^T + b_ih            M=8192 N=4096 K=1024
    gemm_nt<128, 128, 16, 8, 8, false>
        <<<dim3(8192 / 128, 4096 / 128), 256, 0, stream>>>(
            F, 1024, W_ih, 1024, b_ih, Gx, 4096, 8192, 4096, 1024);

    // Pre-pack W_hh into split-bf16 fragments (overwrites F region)
    pack_whh<<<dim3(2048), dim3(256), 0, stream>>>(W_hh, Wf);

    // out = b_cls (scores accumulated atomically by lstm_step)
    out_init<<<dim3(64), dim3(256), 0, stream>>>(out, b_cls);

    // Phase C: 64 fused recurrent steps
    for (int t = 0; t < 64; ++t) {
        lstm_step<<<dim3(256), dim3(256), 0, stream>>>(
            Gx, b_hh, Wf, hfrag, c, W_cls, out, t);
    }
}

// Round 3
// 1450.167 us; speedup vs baseline: 3.9003x; 1.7605x over previous
//
#include <hip/hip_runtime.h>
#include <math.h>

// ---------------------------------------------------------------------------
// DiscriminatorLSTM: B=128, T=64, FEAT=4096, FUSION=1024, H=1024, C=2
//
// All three big GEMMs now run on matrix cores via split-bf16 (hi/lo):
//   value = hi + lo, product = ah*bh + al*bh + ah*bl  (~2^-17 rel error)
//
// Phase A (MFMA): Fh/Fl[8192,1024] = split(relu(X @ W_feat^T + b_feat))
// Phase B (MFMA): Gx[8192,4096]    = (Fh+Fl) @ W_ih^T + b_ih   (f32 out)
// pack_whh: W_hh -> split-bf16 B-fragment layout (16 MB)
// Phase C: 64x fused lstm_step (MFMA recurrence + cell + classifier)
//
// Workspace (<= 161 MB, proven in rounds 1-2):
//   [0, 32MB)    Fh (16 MB) + Fl (16 MB). After phase B overlaid with:
//                Wf (16 MB @ 0), hfrag (1 MB @ 16MB), c (@ 17MB)
//   [32MB,160MB) Gx
// ---------------------------------------------------------------------------

typedef __attribute__((ext_vector_type(8))) short short8v;   // 8 bf16
typedef __attribute__((ext_vector_type(4))) float f32x4;

#define WF_LO_OFF 8388608u
#define HF_BUF    524288
#define HF_HL     262144
#define HF_MT     32768

__device__ __forceinline__ unsigned short f2bf(float f) {   // RNE f32->bf16
    unsigned u = __builtin_bit_cast(unsigned, f);
    u = (u + 0x7fffu + ((u >> 16) & 1u)) >> 16;
    return (unsigned short)u;
}
__device__ __forceinline__ float bf2f(unsigned short b) {
    unsigned u = ((unsigned)b) << 16;
    return __builtin_bit_cast(float, u);
}
__device__ __forceinline__ void split8(const float* f, short8v& hi, short8v& lo) {
#pragma unroll
    for (int e = 0; e < 8; ++e) {
        unsigned short h = f2bf(f[e]);
        hi[e] = (short)h;
        lo[e] = (short)f2bf(f[e] - bf2f(h));
    }
}

// ------------------- split-bf16 MFMA GEMM  (C = A @ B^T) -------------------
// A: f32 [M,K] (A_SPLIT=false) or pre-split u16 hi/lo (A_SPLIT=true)
// B: f32 [N,K], converted on the fly.  Out: f32 C, or split Ch/Cl.
// 128x128 tile, BK=32, 4 waves, fragment-packed LDS (conflict-free).
template<bool A_SPLIT, bool RELU, bool OUT_SPLIT>
__global__ __launch_bounds__(256)
void gemm_split(const float* __restrict__ Af,
                const unsigned short* __restrict__ Ah,
                const unsigned short* __restrict__ Al, int lda,
                const float* __restrict__ B, int ldb,
                const float* __restrict__ bias,
                float* __restrict__ C,
                unsigned short* __restrict__ Ch,
                unsigned short* __restrict__ Cl, int ldc,
                int K)
{
    __shared__ short8v AsH[8][64];   // [m-frag][lane], 1 KB per fragment
    __shared__ short8v AsL[8][64];
    __shared__ short8v BsH[8][64];
    __shared__ short8v BsL[8][64];

    const int tid = threadIdx.x;
    const int l   = tid & 63;
    const int w   = tid >> 6;
    const int wm  = w & 1, wn = w >> 1;      // wave -> 64x64 quadrant
    const int bm  = blockIdx.x * 128, bn = blockIdx.y * 128;

    const int sm    = tid >> 2;              // staging row/col 0..63 (then +64)
    const int sk8   = (tid & 3) * 8;         // k-octet within BK=32
    const int slane = (sm & 15) | ((sk8 >> 3) << 4);
    const int smf   = sm >> 4;               // fragment 0..3 (then +4)

    f32x4 acc[4][4];
#pragma unroll
    for (int i = 0; i < 4; ++i)
#pragma unroll
        for (int j = 0; j < 4; ++j)
#pragma unroll
            for (int r = 0; r < 4; ++r) acc[i][j][r] = 0.f;

    for (int k0 = 0; k0 < K; k0 += 32) {
        // ---- stage A tile ----
        if constexpr (A_SPLIT) {
            const size_t o0 = (size_t)(bm + sm) * lda + k0 + sk8;
            const size_t o1 = (size_t)(bm + sm + 64) * lda + k0 + sk8;
            AsH[smf][slane]     = *(const short8v*)(Ah + o0);
            AsL[smf][slane]     = *(const short8v*)(Al + o0);
            AsH[smf + 4][slane] = *(const short8v*)(Ah + o1);
            AsL[smf + 4][slane] = *(const short8v*)(Al + o1);
        } else {
            float fa[8], fb[8];
            const float* p0 = Af + (size_t)(bm + sm) * lda + k0 + sk8;
            const float* p1 = Af + (size_t)(bm + sm + 64) * lda + k0 + sk8;
            *(float4*)(fa)     = *(const float4*)(p0);
            *(float4*)(fa + 4) = *(const float4*)(p0 + 4);
            *(float4*)(fb)     = *(const float4*)(p1);
            *(float4*)(fb + 4) = *(const float4*)(p1 + 4);
            short8v hi, lo;
            split8(fa, hi, lo);
            AsH[smf][slane] = hi; AsL[smf][slane] = lo;
            split8(fb, hi, lo);
            AsH[smf + 4][slane] = hi; AsL[smf + 4][slane] = lo;
        }
        // ---- stage B tile (always f32 -> split) ----
        {
            float fa[8], fb[8];
            const float* p0 = B + (size_t)(bn + sm) * ldb + k0 + sk8;
            const float* p1 = B + (size_t)(bn + sm + 64) * ldb + k0 + sk8;
            *(float4*)(fa)     = *(const float4*)(p0);
            *(float4*)(fa + 4) = *(const float4*)(p0 + 4);
            *(float4*)(fb)     = *(const float4*)(p1);
            *(float4*)(fb + 4) = *(const float4*)(p1 + 4);
            short8v hi, lo;
            split8(fa, hi, lo);
            BsH[smf][slane] = hi; BsL[smf][slane] = lo;
            split8(fb, hi, lo);
            BsH[smf + 4][slane] = hi; BsL[smf + 4][slane] = lo;
        }
        __syncthreads();

        short8v a_h[4], a_l[4];
#pragma unroll
        for (int i = 0; i < 4; ++i) {
            a_h[i] = AsH[wm * 4 + i][l];
            a_l[i] = AsL[wm * 4 + i][l];
        }
#pragma unroll
        for (int j = 0; j < 4; ++j) {
            const short8v b_h = BsH[wn * 4 + j][l];
            const short8v b_l = BsL[wn * 4 + j][l];
#pragma unroll
            for (int i = 0; i < 4; ++i) {
                acc[i][j] = __builtin_amdgcn_mfma_f32_16x16x32_bf16(a_h[i], b_h, acc[i][j], 0, 0, 0);
                acc[i][j] = __builtin_amdgcn_mfma_f32_16x16x32_bf16(a_l[i], b_h, acc[i][j], 0, 0, 0);
                acc[i][j] = __builtin_amdgcn_mfma_f32_16x16x32_bf16(a_h[i], b_l, acc[i][j], 0, 0, 0);
            }
        }
        __syncthreads();
    }

    // ---- epilogue:  D row=(l>>4)*4+r, col=l&15 within each 16x16 frag ----
    const int row0 = bm + wm * 64 + (l >> 4) * 4;
    const int col0 = bn + wn * 64 + (l & 15);
#pragma unroll
    for (int i = 0; i < 4; ++i) {
#pragma unroll
        for (int j = 0; j < 4; ++j) {
            const int col = col0 + j * 16;
            const float bs = bias[col];
#pragma unroll
            for (int r = 0; r < 4; ++r) {
                const int row = row0 + i * 16 + r;
                float v = acc[i][j][r] + bs;
                if (RELU) v = fmaxf(v, 0.f);
                if (OUT_SPLIT) {
                    unsigned short h = f2bf(v);
                    Ch[(size_t)row * ldc + col] = h;
                    Cl[(size_t)row * ldc + col] = f2bf(v - bf2f(h));
                } else {
                    C[(size_t)row * ldc + col] = v;
                }
            }
        }
    }
}

// --------------- W_hh -> split-bf16 B-fragment pre-pack --------------------
__global__ void pack_whh(const float* __restrict__ W, char* __restrict__ Wf) {
    int gid = blockIdx.x * blockDim.x + threadIdx.x;   // < 524288
    int l = gid & 63, fid = gid >> 6;
    int nt = fid & 1, kc = (fid >> 1) & 31, g = (fid >> 6) & 3, ng = fid >> 8;
    int n = g * 1024 + ng * 32 + nt * 16 + (l & 15);
    int k = kc * 32 + (l >> 4) * 8;
    const float* src = W + (size_t)n * 1024 + k;
    short8v hi, lo;
#pragma unroll
    for (int e = 0; e < 8; ++e) {
        float v = src[e];
        unsigned short hb = f2bf(v);
        hi[e] = (short)hb;
        lo[e] = (short)f2bf(v - bf2f(hb));
    }
    size_t off = (size_t)fid * 1024 + (size_t)l * 16;
    *(short8v*)(Wf + off) = hi;
    *(short8v*)(Wf + WF_LO_OFF + off) = lo;
}

__global__ void out_init(float* __restrict__ out, const float* __restrict__ b_cls) {
    int i = blockIdx.x * blockDim.x + threadIdx.x;
    if (i < 16384) out[i] = b_cls[i & 1];
}

// --------------------------- fused LSTM step -------------------------------
__global__ __launch_bounds__(256)
void lstm_step(const float* __restrict__ Gx,
               const float* __restrict__ b_hh,
               const char*  __restrict__ Wf,
               char*        __restrict__ hfrag,
               float*       __restrict__ c,
               const float* __restrict__ Wc,
               float*       __restrict__ out,
               int t)
{
    __shared__ float gates_s[4][16][33];
    __shared__ float h_s[16][33];
    __shared__ float Wc_s[2][32];

    const int tid  = threadIdx.x;
    const int bid  = blockIdx.x;
    const int g    = tid >> 6;
    const int l    = tid & 63;
    const int slot = bid >> 3;
    const int m_tile = slot & 7;
    const int ng   = (bid & 7) * 4 + (slot >> 3);

    if (tid < 64) Wc_s[tid >> 5][tid & 31] =
        Wc[(size_t)(tid >> 5) * 1024 + ng * 32 + (tid & 31)];

    const int lhi = l >> 4;
    const int llo = l & 15;

    const float bh0 = b_hh[g * 1024 + ng * 32 + llo];
    const float bh1 = b_hh[g * 1024 + ng * 32 + 16 + llo];

    f32x4 acc0, acc1;
    {
        const int colg0 = g * 1024 + ng * 32 + llo;
#pragma unroll
        for (int r = 0; r < 4; ++r) {
            int brow = m_tile * 16 + lhi * 4 + r;
            const float* gp = Gx + ((size_t)brow * 64 + t) * 4096 + colg0;
            acc0[r] = gp[0]  + bh0;
            acc1[r] = gp[16] + bh1;
        }
    }

    if (t > 0) {
        const char* ha = hfrag + ((t - 1) & 1) * HF_BUF + m_tile * HF_MT + l * 16;
        const char* hb = ha + HF_HL;
        const char* wbase = Wf + (size_t)((ng * 4 + g) * 64) * 1024 + l * 16;
#pragma unroll 4
        for (int kc = 0; kc < 32; ++kc) {
            short8v ah = *(const short8v*)(ha + kc * 1024);
            short8v al = *(const short8v*)(hb + kc * 1024);
            const char* w0 = wbase + kc * 2048;
            short8v bhv0 = *(const short8v*)(w0);
            short8v bhv1 = *(const short8v*)(w0 + 1024);
            short8v blv0 = *(const short8v*)(w0 + WF_LO_OFF);
            short8v blv1 = *(const short8v*)(w0 + WF_LO_OFF + 1024);
            acc0 = __builtin_amdgcn_mfma_f32_16x16x32_bf16(ah, bhv0, acc0, 0, 0, 0);
            acc1 = __builtin_amdgcn_mfma_f32_16x16x32_bf16(ah, bhv1, acc1, 0, 0, 0);
            acc0 = __builtin_amdgcn_mfma_f32_16x16x32_bf16(al, bhv0, acc0, 0, 0, 0);
            acc1 = __builtin_amdgcn_mfma_f32_16x16x32_bf16(al, bhv1, acc1, 0, 0, 0);
            acc0 = __builtin_amdgcn_mfma_f32_16x16x32_bf16(ah, blv0, acc0, 0, 0, 0);
            acc1 = __builtin_amdgcn_mfma_f32_16x16x32_bf16(ah, blv1, acc1, 0, 0, 0);
        }
    }

#pragma unroll
    for (int r = 0; r < 4; ++r) {
        gates_s[g][lhi * 4 + r][llo]      = acc0[r];
        gates_s[g][lhi * 4 + r][16 + llo] = acc1[r];
    }
    __syncthreads();

    for (int e = tid; e < 512; e += 256) {
        int m  = e >> 5;
        int cc = e & 31;
        float ig = gates_s[0][m][cc], fg = gates_s[1][m][cc];
        float gg = gates_s[2][m][cc], og = gates_s[3][m][cc];
        ig = 1.f / (1.f + __expf(-ig));
        fg = 1.f / (1.f + __expf(-fg));
        gg = tanhf(gg);
        og = 1.f / (1.f + __expf(-og));
        size_t cidx = (size_t)(m_tile * 16 + m) * 1024 + ng * 32 + cc;
        float cp = (t > 0) ? c[cidx] : 0.f;
        float cn = fg * cp + ig * gg;
        float hn = og * tanhf(cn);
        c[cidx] = cn;
        h_s[m][cc] = hn;
    }
    __syncthreads();

    if (g < 2) {
        short8v v;
#pragma unroll
        for (int e = 0; e < 8; ++e) {
            float hv = h_s[llo][lhi * 8 + e];
            unsigned short hb_ = f2bf(hv);
            v[e] = (short)(g == 0 ? hb_ : f2bf(hv - bf2f(hb_)));
        }
        char* dst = hfrag + (t & 1) * HF_BUF + g * HF_HL + m_tile * HF_MT
                  + ng * 1024 + l * 16;
        *(short8v*)dst = v;
    } else if (g == 2 && l < 32) {
        int m = l & 15, cls = l >> 4;
        float s = 0.f;
#pragma unroll
        for (int cc = 0; cc < 32; ++cc) s += h_s[m][cc] * Wc_s[cls][cc];
        atomicAdd(out + ((size_t)(m_tile * 16 + m) * 64 + t) * 2 + cls, s);
    }
}

// ---------------------------------------------------------------------------
extern "C" void kernel_launch(void* const* d_in, const int* in_sizes, int n_in,
                              void* d_out, int out_size, void* d_ws, size_t ws_size,
                              hipStream_t stream) {
    const float* x      = (const float*)d_in[0];
    const float* W_feat = (const float*)d_in[1];
    const float* b_feat = (const float*)d_in[2];
    const float* W_ih   = (const float*)d_in[3];
    const float* b_ih   = (const float*)d_in[4];
    const float* W_hh   = (const float*)d_in[5];
    const float* b_hh   = (const float*)d_in[6];
    const float* W_cls  = (const float*)d_in[7];
    const float* b_cls  = (const float*)d_in[8];
    float* out = (float*)d_out;

    char* ws = (char*)d_ws;
    unsigned short* Fh = (unsigned short*)ws;              // 16 MB
    unsigned short* Fl = (unsigned short*)(ws + 16777216); // 16 MB
    float* Gx    = (float*)(ws + 33554432);                // 128 MB
    char*  Wf    = ws;                                     // 16 MB (after B)
    char*  hfrag = ws + 16777216;                          // 1 MB
    float* c     = (float*)(ws + 17825792);                // 512 KB

    // Phase A: Fh/Fl = split(relu(X @ W_feat^T + b_feat))  M=8192 N=1024 K=4096
    gemm_split<false, true, true>
        <<<dim3(64, 8), 256, 0, stream>>>(
            x, nullptr, nullptr, 4096, W_feat, 4096, b_feat,
            nullptr, Fh, Fl, 1024, 4096);

    // Phase B: Gx = F @ W_ih^T + b_ih   M=8192 N=4096 K=1024
    gemm_split<true, false, false>
        <<<dim3(64, 32), 256, 0, stream>>>(
            nullptr, Fh, Fl, 1024, W_ih, 1024, b_ih,
            Gx, nullptr, nullptr, 4096, 1024);

    // Pre-pack W_hh into split-bf16 fragments (overwrites Fh region)
    pack_whh<<<dim3(2048), dim3(256), 0, stream>>>(W_hh, Wf);

    out_init<<<dim3(64), dim3(256), 0, stream>>>(out, b_cls);

    for (int t = 0; t < 64; ++t) {
        lstm_step<<<dim3(256), dim3(256), 0, stream>>>(
            Gx, b_hh, Wf, hfrag, c, W_cls, out, t);
    }
}